// Round 12
// baseline (322.551 us; speedup 1.0000x reference)
//
#include <hip/hip_runtime.h>

#define T_LEN 8000
#define NTPB 125
#define NBLK 250
#define NLAYER 30
#define GUARD 512
#define HROWS (GUARD + T_LEN)
#define SLAB (HROWS * 128)          // shorts per h slab (level,batch)
#define INV_SQRT2 0.70710678118f

typedef short bf16x8 __attribute__((ext_vector_type(8)));
typedef unsigned uint2v __attribute__((ext_vector_type(2)));
typedef unsigned uint4v __attribute__((ext_vector_type(4)));
typedef float f32x4 __attribute__((ext_vector_type(4)));

// ---- LDS layout (shorts). slot = 512 shorts (64 rows x 8 ch) ----
#define R_HT  0          // h[t] 16 slots; x tile spans slots 0..31
#define R_OUT 8192       // gated out / y
#define R_CND 16384      // cond (12 slots; k=80 -> 1.0 bias col)
#define WA    22528      // 64 KB weight buffer (32768 shorts)
#define WB    55296      // 48 KB weight buffer (24576 shorts)
#define LDS_SHORTS 79872 // 156 KB

// ---- weight pack: per layer 26 klines (kline = 4096 shorts = 8 KB) ----
// kline order: d1/g pairs (0-7), c/cg pairs (8-13), d0 (14-17), r/s pairs (18-25)
#define LS 106496
#define CH2 32768      // klines 8..13  (c/cg)      -> WB  (48 KB)
#define CH3 57344      // klines 14..19 (d0 + rs p0) -> WA (48 KB)
#define CH4 81920      // klines 20..25 (rs p1-3)    -> WB  (48 KB)
#define IN_OFF   3194880
#define OUT1_OFF 3227648
#define OUT2_OFF 3244032

#define WAITV(N) asm volatile("s_waitcnt vmcnt(" #N ")" ::: "memory")
#define LGKM0    asm volatile("s_waitcnt lgkmcnt(0)" ::: "memory")
#define BAR      asm volatile("s_barrier" ::: "memory")

__device__ __forceinline__ unsigned short f2bf_u(float f) {
    union { float f; unsigned u; } v; v.f = f;
    unsigned u = v.u + 0x7FFFu + ((v.u >> 16) & 1u);
    return (unsigned short)(u >> 16);
}
__device__ __forceinline__ short f2bf(float f) { return (short)f2bf_u(f); }

__device__ __forceinline__ unsigned cvtpk(float lo, float hi) {
    unsigned r;
    asm("v_cvt_pk_bf16_f32 %0, %1, %2" : "=v"(r) : "v"(lo), "v"(hi));
    return r;
}
__device__ __forceinline__ float gated_act(float av, float gv) {
    float e  = __expf(-2.f * fabsf(av));
    float th = (1.f - e) * __builtin_amdgcn_rcpf(1.f + e);
    th = (av < 0.f) ? -th : th;
    float sg = __builtin_amdgcn_rcpf(1.f + __expf(-gv));
    return th * sg;
}
__device__ __forceinline__ void ldg16_sc1(bf16x8* d, const short* p) {
    asm volatile("global_load_dwordx4 %0, %1, off sc1" : "=v"(*d) : "v"(p));
}
__device__ __forceinline__ void stg8_sc1(short* p, uint2v v) {
    asm volatile("global_store_dwordx2 %0, %1, off sc1" : : "v"(p), "v"(v) : "memory");
}
__device__ __forceinline__ void st_flag(int* p, int v) {
    __hip_atomic_store(p, v, __ATOMIC_RELAXED, __HIP_MEMORY_SCOPE_AGENT);
}
__device__ __forceinline__ void wait_ge(const int* p, int v) {
    while (__hip_atomic_load(p, __ATOMIC_RELAXED, __HIP_MEMORY_SCOPE_AGENT) < v)
        __builtin_amdgcn_s_sleep(1);
}
__device__ __forceinline__ f32x4 mfma_(bf16x8 a, bf16x8 b, f32x4 c) {
    return __builtin_amdgcn_mfma_f32_16x16x32_bf16(a, b, c, 0, 0, 0);
}
__device__ __forceinline__ void gload_lds16(const short* g, short* l) {
    __builtin_amdgcn_global_load_lds(
        (const __attribute__((address_space(1))) unsigned int*)g,
        (__attribute__((address_space(3))) unsigned int*)l, 16, 0, 0);
}
// 16-wave staging: R half-klines of 16 KB each (R=2 -> 32 KB, 3 -> 48 KB, 4 -> 64 KB)
template<int R>
__device__ __forceinline__ void stageK(const short* src, short* dst, int wv, int lane) {
#pragma unroll
    for (int r = 0; r < R; ++r) {
        int off = (r * 16 + wv) * 512;
        gload_lds16(src + off + lane * 8, dst + off);
    }
}

// two A-streams (pair-interleaved chunk), B from LDS slot table (R6-verified)
template<int NP>
__device__ __forceinline__ void pairN(const short* wb, const short* sm, int boff,
                                      int ks0, int lg, int awoff,
                                      f32x4* ac0, f32x4* ac1)
{
#pragma unroll
    for (int p = 0; p < NP; ++p) {
        bf16x8 B = *(const bf16x8*)&sm[boff + ((ks0 + p) * 4 + lg) * 512];
#pragma unroll
        for (int mt = 0; mt < 2; ++mt) {
            bf16x8 a0 = *(const bf16x8*)&wb[p * 8192 + awoff + mt * 512];
            ac0[mt] = mfma_(a0, B, ac0[mt]);
            bf16x8 a1 = *(const bf16x8*)&wb[p * 8192 + 4096 + awoff + mt * 512];
            ac1[mt] = mfma_(a1, B, ac1[mt]);
        }
    }
}
template<int NP>
__device__ __forceinline__ void singleN(const short* wb, const short* sm, int boff,
                                        int ks0, int lg, int awoff, f32x4* ac)
{
#pragma unroll
    for (int p = 0; p < NP; ++p) {
        bf16x8 B = *(const bf16x8*)&sm[boff + ((ks0 + p) * 4 + lg) * 512];
#pragma unroll
        for (int mt = 0; mt < 2; ++mt) {
            bf16x8 a = *(const bf16x8*)&wb[p * 4096 + awoff + mt * 512];
            ac[mt] = mfma_(a, B, ac[mt]);
        }
    }
}

// ---------------- weight pack + flag/guard zero (R6 verbatim) ----------------
__global__ __launch_bounds__(256) void k_pack(
    const float* __restrict__ dil_w, const float* __restrict__ gate_w,
    const float* __restrict__ cond_w, const float* __restrict__ condg_w,
    const float* __restrict__ res_w, const float* __restrict__ skip_w,
    const float* __restrict__ input_w, const float* __restrict__ out1_w,
    const float* __restrict__ out2_w,
    const float* __restrict__ dil_b, const float* __restrict__ cond_b,
    const float* __restrict__ gate_b, const float* __restrict__ condg_b,
    short* __restrict__ wp, short* __restrict__ hbt, int* __restrict__ flg)
{
    int gid = blockIdx.x * 256 + threadIdx.x;
    if (gid < 512) flg[gid] = 0;
    {
        int g2 = gid - 512;
        if (g2 >= 0 && g2 < 262144) {      // zero guard rows of 8 slabs
            unsigned* hb32 = (unsigned*)hbt;
            int slab = g2 >> 15, off = g2 & 32767;
            hb32[(size_t)slab * (SLAB / 2) + off] = 0u;
        }
    }
    if (gid >= 6400 * 64) return;
    int fid = gid >> 6, lane = gid & 63;
    int lr = lane & 15, lg = lane >> 4;
    float v[8];
    if (fid < 6240) {
        int layer = fid / 208;
        int r = fid - layer * 208;
        int kl = r >> 3, f = r & 7;
        int m = f * 16 + lr;
        size_t mi = (size_t)layer * 128 + m;
        int mat, ks;
        if      (kl < 8)  { mat = (kl & 1) ? 2 : 1; ks = kl >> 1; }
        else if (kl < 14) { mat = (kl & 1) ? 4 : 3; ks = (kl - 8) >> 1; }
        else if (kl < 18) { mat = 0; ks = kl - 14; }
        else              { mat = (kl & 1) ? 6 : 5; ks = (kl - 18) >> 1; }
        int kb = ks * 32 + lg * 8;
#pragma unroll
        for (int e = 0; e < 8; ++e) {
            int k = kb + e;
            float val;
            switch (mat) {
                case 0:  val = dil_w[(mi * 128 + k) * 2];     break;
                case 1:  val = dil_w[(mi * 128 + k) * 2 + 1]; break;
                case 2:  val = gate_w[mi * 128 + k]; break;
                case 3:  val = (k < 80) ? cond_w[mi * 80 + k]
                               : ((k == 80) ? dil_b[mi] + cond_b[mi] : 0.f); break;
                case 4:  val = (k < 80) ? condg_w[mi * 80 + k]
                               : ((k == 80) ? gate_b[mi] + condg_b[mi] : 0.f); break;
                case 5:  val = res_w[mi * 128 + k]; break;
                default: val = skip_w[mi * 128 + k]; break;
            }
            v[e] = val;
        }
    } else if (fid < 6304) {
        int f = fid - 6240; int ks = f >> 3, fr = f & 7;
        int m = fr * 16 + lr; int kb = ks * 32 + lg * 8;
#pragma unroll
        for (int e = 0; e < 8; ++e) v[e] = input_w[(size_t)m * 256 + kb + e];
    } else if (fid < 6336) {
        int f = fid - 6304; int ks = f >> 3, fr = f & 7;
        int m = fr * 16 + lr; int kb = ks * 32 + lg * 8;
#pragma unroll
        for (int e = 0; e < 8; ++e) v[e] = out1_w[(size_t)m * 128 + kb + e];
    } else {
        int f = fid - 6336; int mt = f & 15; int ks = f >> 4;
        int m = mt * 16 + lr; int kb = ks * 32 + lg * 8;
#pragma unroll
        for (int e = 0; e < 8; ++e) v[e] = out2_w[(size_t)m * 128 + kb + e];
    }
    short* dst = wp + (size_t)fid * 512 + lane * 8;
#pragma unroll
    for (int e = 0; e < 8; ++e) dst[e] = f2bf(v[e]);
}

// ---------------- persistent fused WaveNet: 16 waves, 5-phase layer ----------------
__global__ __launch_bounds__(1024, 4) void k_wavenet(
    const float* __restrict__ x, const float* __restrict__ cond,
    const short* __restrict__ wp, short* __restrict__ hbt,
    const float* __restrict__ ib, const float* __restrict__ rbias,
    const float* __restrict__ sbias, const float* __restrict__ b1,
    const float* __restrict__ b2, float* __restrict__ outp,
    int* __restrict__ rdy, int* __restrict__ dn)
{
    __shared__ __align__(16) short sm[LDS_SHORTS];   // 156 KB

    const int tid  = threadIdx.x;
    const int lane = tid & 63;
    const int wv   = __builtin_amdgcn_readfirstlane(tid >> 6);   // 0..15
    const int wm   = wv & 3;
    const int wn   = wv >> 2;
    const int lr   = lane & 15, lg = lane >> 4;
    const int bidx = blockIdx.x;
    const int b    = bidx / NTPB;
    const int ti   = bidx - b * NTPB;
    const int t0   = ti * 64;
    const int tl   = wn * 16 + lr;
    const int tg   = t0 + tl;
    const int tl8  = tl * 8;
    const int lane8 = lane * 8;
    const int awoff = wm * 1024 + lane8;
    const int chA  = wm * 32 + lg * 4;
    const int kbA  = wm * 4 + (lg >> 1);
    const int e0   = (lg & 1) * 4;

    short* const wA = (short*)&sm[WA];
    short* const wB = (short*)&sm[WB];

    // ---- stage input-conv weights (64 KB -> WA) + x tile + cond ----
    stageK<4>(wp + IN_OFF, wA, wv, lane);
    {
        const float* xb = x + (size_t)b * 256 * T_LEN + t0 + lane;
#pragma unroll
        for (int it = 0; it < 2; ++it) {
            int kb = wv * 2 + it;              // 0..31
            unsigned pk[4];
#pragma unroll
            for (int e = 0; e < 4; ++e)
                pk[e] = cvtpk(xb[(size_t)(kb * 8 + 2 * e) * T_LEN],
                              xb[(size_t)(kb * 8 + 2 * e + 1) * T_LEN]);
            *(uint4v*)&sm[(kb * 64 + lane) * 8] = *(uint4v*)pk;
        }
        if (wv < 12) {
            const float* cb = cond + (size_t)b * 80 * T_LEN + t0 + lane;
            unsigned pk[4];
#pragma unroll
            for (int e = 0; e < 4; ++e) {
                int c0 = wv * 8 + 2 * e, c1 = c0 + 1;
                float v0 = (c0 < 80) ? cb[(size_t)c0 * T_LEN] : ((c0 == 80) ? 1.f : 0.f);
                float v1 = (c1 < 80) ? cb[(size_t)c1 * T_LEN] : 0.f;
                pk[e] = cvtpk(v0, v1);
            }
            *(uint4v*)&sm[R_CND + (wv * 64 + lane) * 8] = *(uint4v*)pk;
        }
    }
    __syncthreads();

    // ---- input conv ----
    f32x4 hres[2] = {{0.f,0.f,0.f,0.f},{0.f,0.f,0.f,0.f}};
    {
        f32x4 acc[2] = {{0.f,0.f,0.f,0.f},{0.f,0.f,0.f,0.f}};
        singleN<4>(wA, sm, tl8, 0, lg, awoff, acc);
        singleN<4>(wA + 16384, sm, tl8, 4, lg, awoff, acc);
#pragma unroll
        for (int mt = 0; mt < 2; ++mt) {
            int cb0 = chA + mt * 16;
            f32x4 bv = {ib[cb0], ib[cb0 + 1], ib[cb0 + 2], ib[cb0 + 3]};
            hres[mt] = acc[mt] + bv;
        }
    }
    __syncthreads();   // all waves done reading x slots / WA
    {
        short* hrow = hbt + (size_t)b * SLAB + (size_t)(GUARD + tg) * 128 + chA;
#pragma unroll
        for (int mt = 0; mt < 2; ++mt) {
            uint2v hv = {cvtpk(hres[mt][0], hres[mt][1]), cvtpk(hres[mt][2], hres[mt][3])};
            stg8_sc1(hrow + mt * 16, hv);
            *(uint2v*)&sm[R_HT + ((kbA + mt * 2) * 64 + tl) * 8 + e0] = hv;
        }
    }
    stageK<4>(wp, wA, wv, lane);       // layer-0 ch1 (d1/g) -> WA
    asm volatile("s_waitcnt vmcnt(0)" ::: "memory");
    __syncthreads();
    if (tid == 0) st_flag(&rdy[bidx], 1);

    f32x4 skp[2] = {{0.f,0.f,0.f,0.f},{0.f,0.f,0.f,0.f}};

    // ---- 30 layers, 5 phases each ----
    for (int li = 0; li < NLAYER; ++li) {
        const int d   = 1 << (li % 10);
        const int ksh = (d + 63) >> 6;
        const short* wl  = wp + (size_t)li * LS;
        const short* hcb = hbt + (size_t)((li & 3) * 2 + b) * SLAB;
        short*       hnb = hbt + (size_t)(((li + 1) & 3) * 2 + b) * SLAB;

        // ---- P1: stage ch2->WB; flag wait; Bg; compute d1/g (4 pair-steps) ----
        stageK<3>(wl + CH2, wB, wv, lane);
        if (lane == 0 && ti >= ksh) wait_ge(&rdy[bidx - ksh], li + 1);
        bf16x8 Bg[4];
        {
            const short* hr = hcb + (size_t)(GUARD + tg - d) * 128 + lg * 8;
#pragma unroll
            for (int ks = 0; ks < 4; ++ks) ldg16_sc1(&Bg[ks], hr + ks * 32);
        }
        f32x4 aa[2] = {{0.f,0.f,0.f,0.f},{0.f,0.f,0.f,0.f}};
        f32x4 ag[2] = {{0.f,0.f,0.f,0.f},{0.f,0.f,0.f,0.f}};
        pairN<4>(wA, sm, R_HT + tl8, 0, lg, awoff, aa, ag);
        __syncthreads();                                   // bar1: ch2+Bg landed
        if (tid == 0) st_flag(&dn[bidx], li + 1);          // Bg retired

        // ---- P2: stage ch3->WA; compute c/cg (3 pair-steps) ----
        stageK<3>(wl + CH3, wA, wv, lane);
        pairN<3>(wB, sm, R_CND + tl8, 0, lg, awoff, aa, ag);
        __syncthreads();                                   // bar2: ch3 landed

        // ---- P3: stage ch4->WB; d0 @ Bg; act -> R_OUT ----
        stageK<3>(wl + CH4, wB, wv, lane);
        {
#pragma unroll
            for (int ks = 0; ks < 4; ++ks) {
#pragma unroll
                for (int mt = 0; mt < 2; ++mt) {
                    bf16x8 a = *(const bf16x8*)&wA[ks * 4096 + awoff + mt * 512];
                    aa[mt] = mfma_(a, Bg[ks], aa[mt]);
                }
            }
        }
#pragma unroll
        for (int mt = 0; mt < 2; ++mt) {
            uint2v ov = {cvtpk(gated_act(aa[mt][0], ag[mt][0]), gated_act(aa[mt][1], ag[mt][1])),
                         cvtpk(gated_act(aa[mt][2], ag[mt][2]), gated_act(aa[mt][3], ag[mt][3]))};
            *(uint2v*)&sm[R_OUT + ((kbA + mt * 2) * 64 + tl) * 8 + e0] = ov;
        }
        __syncthreads();                                   // bar3: ch4 landed, act visible

        // ---- P4: r/s gemms (pair0 from WA+16384, pairs1-3 from WB) ----
        f32x4 ar[2]  = {{0.f,0.f,0.f,0.f},{0.f,0.f,0.f,0.f}};
        f32x4 as2[2] = {{0.f,0.f,0.f,0.f},{0.f,0.f,0.f,0.f}};
        pairN<1>(wA + 16384, sm, R_OUT + tl8, 0, lg, awoff, ar, as2);
        pairN<3>(wB, sm, R_OUT + tl8, 1, lg, awoff, ar, as2);
        {
            const float* rbl = rbias + li * 128 + chA;
            const float* sbl = sbias + li * 128 + chA;
#pragma unroll
            for (int mt = 0; mt < 2; ++mt) {
                f32x4 rbv = {rbl[mt*16], rbl[mt*16+1], rbl[mt*16+2], rbl[mt*16+3]};
                f32x4 sbv = {sbl[mt*16], sbl[mt*16+1], sbl[mt*16+2], sbl[mt*16+3]};
                skp[mt]  = skp[mt] + as2[mt] + sbv;
                hres[mt] = (hres[mt] + ar[mt] + rbv) * INV_SQRT2;
            }
        }
        __syncthreads();                                   // bar4: WA/WB reads done (cheap)

        // ---- P5: h-store + R_HT update; stage next ch1->WA ----
        if (li < NLAYER - 1) {
            if (lane == 0 && li >= 3) {        // WAR vs readers of h^{li-3}
                int d3 = 1 << ((li - 3) % 10);
                int k3 = (d3 + 63) >> 6;
                if (ti + k3 < NTPB) wait_ge(&dn[bidx + k3], li - 2);
            }
            short* hrow = hnb + (size_t)(GUARD + tg) * 128 + chA;
#pragma unroll
            for (int mt = 0; mt < 2; ++mt) {
                uint2v hv = {cvtpk(hres[mt][0], hres[mt][1]), cvtpk(hres[mt][2], hres[mt][3])};
                stg8_sc1(hrow + mt * 16, hv);
                *(uint2v*)&sm[R_HT + ((kbA + mt * 2) * 64 + tl) * 8 + e0] = hv;
            }
            stageK<4>(wl + LS, wA, wv, lane);  // next layer's ch1 (d1/g)
            WAITV(4);                          // h-stores drained (4 ch1 ops may remain)
            LGKM0; BAR;                        // bar5
            if (tid == 0) st_flag(&rdy[bidx], li + 2);
        } else {
            __syncthreads();                   // final layer: nothing staged
        }
    }

    // ---- output head ----
#pragma unroll
    for (int mt = 0; mt < 2; ++mt) {           // skip -> R_HT (bf16)
        uint2v sv = {cvtpk(skp[mt][0], skp[mt][1]), cvtpk(skp[mt][2], skp[mt][3])};
        *(uint2v*)&sm[R_HT + ((kbA + mt * 2) * 64 + tl) * 8 + e0] = sv;
    }
    stageK<2>(wp + OUT1_OFF, wA, wv, lane);            // out1 -> WA[0:16383]
    stageK<2>(wp + OUT2_OFF, wA + 16384, wv, lane);    // out2 ks0-1 -> WA[16384:]
    stageK<2>(wp + OUT2_OFF + 16384, wB, wv, lane);    // out2 ks2-3 -> WB
    __syncthreads();
    f32x4 ay[2] = {{0.f,0.f,0.f,0.f},{0.f,0.f,0.f,0.f}};
    singleN<4>(wA, sm, R_HT + tl8, 0, lg, awoff, ay);
#pragma unroll
    for (int mt = 0; mt < 2; ++mt) {           // y = relu(. + b1) -> R_OUT
        int cb0 = chA + mt * 16;
        float y0 = fmaxf(ay[mt][0] + b1[cb0],     0.f);
        float y1 = fmaxf(ay[mt][1] + b1[cb0 + 1], 0.f);
        float y2 = fmaxf(ay[mt][2] + b1[cb0 + 2], 0.f);
        float y3 = fmaxf(ay[mt][3] + b1[cb0 + 3], 0.f);
        uint2v yv = {cvtpk(y0, y1), cvtpk(y2, y3)};
        *(uint2v*)&sm[R_OUT + ((kbA + mt * 2) * 64 + tl) * 8 + e0] = yv;
    }
    __syncthreads();
    f32x4 ao[4] = {{0.f,0.f,0.f,0.f},{0.f,0.f,0.f,0.f},
                   {0.f,0.f,0.f,0.f},{0.f,0.f,0.f,0.f}};
    {
        const short* w2a = wA + 16384;
        const short* w2b = wB;
#pragma unroll
        for (int ksp = 0; ksp < 2; ++ksp) {
            bf16x8 B = *(const bf16x8*)&sm[R_OUT + tl8 + (ksp * 4 + lg) * 512];
#pragma unroll
            for (int mt = 0; mt < 4; ++mt) {
                int fg = 4 * wm + mt;
                bf16x8 A = *(const bf16x8*)&w2a[(ksp * 2 + (fg >> 3)) * 4096 + (fg & 7) * 512 + lane8];
                ao[mt] = mfma_(A, B, ao[mt]);
            }
        }
#pragma unroll
        for (int ksp = 0; ksp < 2; ++ksp) {
            bf16x8 B = *(const bf16x8*)&sm[R_OUT + tl8 + ((2 + ksp) * 4 + lg) * 512];
#pragma unroll
            for (int mt = 0; mt < 4; ++mt) {
                int fg = 4 * wm + mt;
                bf16x8 A = *(const bf16x8*)&w2b[(ksp * 2 + (fg >> 3)) * 4096 + (fg & 7) * 512 + lane8];
                ao[mt] = mfma_(A, B, ao[mt]);
            }
        }
    }
#pragma unroll
    for (int mt = 0; mt < 4; ++mt) {
        int ch2 = wm * 64 + mt * 16 + lg * 4;
        float* op = outp + ((size_t)(b * 256 + ch2)) * T_LEN + tg;
        op[0]         = ao[mt][0] + b2[ch2];
        op[T_LEN]     = ao[mt][1] + b2[ch2 + 1];
        op[2 * T_LEN] = ao[mt][2] + b2[ch2 + 2];
        op[3 * T_LEN] = ao[mt][3] + b2[ch2 + 3];
    }
}

extern "C" void kernel_launch(void* const* d_in, const int* in_sizes, int n_in,
                              void* d_out, int out_size, void* d_ws, size_t ws_size,
                              hipStream_t stream)
{
    const float* x       = (const float*)d_in[0];
    const float* cond    = (const float*)d_in[1];
    const float* input_w = (const float*)d_in[2];
    const float* input_b = (const float*)d_in[3];
    const float* dil_w   = (const float*)d_in[4];
    const float* dil_b   = (const float*)d_in[5];
    const float* gate_w  = (const float*)d_in[6];
    const float* gate_b  = (const float*)d_in[7];
    const float* cond_w  = (const float*)d_in[8];
    const float* cond_b  = (const float*)d_in[9];
    const float* condg_w = (const float*)d_in[10];
    const float* condg_b = (const float*)d_in[11];
    const float* res_w   = (const float*)d_in[12];
    const float* res_b   = (const float*)d_in[13];
    const float* skip_w  = (const float*)d_in[14];
    const float* skip_b  = (const float*)d_in[15];
    const float* out1_w  = (const float*)d_in[16];
    const float* out1_b  = (const float*)d_in[17];
    const float* out2_w  = (const float*)d_in[18];
    const float* out2_b  = (const float*)d_in[19];
    float* outp = (float*)d_out;

    short* wpk = (short*)d_ws;                         // 6400*512 shorts
    short* hbt = wpk + (size_t)6400 * 512;             // 8 slabs (4 levels x 2 batches)
    int*   flg = (int*)(hbt + (size_t)8 * SLAB);       // 512 ints
    int*   rdy = flg;
    int*   dn  = flg + 256;

    k_pack<<<1600, 256, 0, stream>>>(dil_w, gate_w, cond_w, condg_w, res_w, skip_w,
                                     input_w, out1_w, out2_w,
                                     dil_b, cond_b, gate_b, condg_b, wpk, hbt, flg);

    void* args[] = {(void*)&x, (void*)&cond, (void*)&wpk, (void*)&hbt,
                    (void*)&input_b, (void*)&res_b, (void*)&skip_b,
                    (void*)&out1_b, (void*)&out2_b, (void*)&outp,
                    (void*)&rdy, (void*)&dn};
    (void)hipLaunchCooperativeKernel((void*)k_wavenet, dim3(NBLK), dim3(1024), args, 0, stream);
}

// Round 13
// 291.092 us; speedup vs baseline: 1.1081x; 1.1081x over previous
//
#include <hip/hip_runtime.h>

#define T_LEN 8000
#define NTPB 125
#define NBLK 250
#define NLAYER 30
#define GUARD 512
#define HROWS (GUARD + T_LEN)
#define SLAB (HROWS * 128)          // shorts per h slab (level,batch)
#define INV_SQRT2 0.70710678118f

typedef short bf16x8 __attribute__((ext_vector_type(8)));
typedef unsigned uint2v __attribute__((ext_vector_type(2)));
typedef unsigned uint4v __attribute__((ext_vector_type(4)));
typedef float f32x4 __attribute__((ext_vector_type(4)));

// ---- LDS layout (shorts). [kb][t][8] slots, slot = 512 shorts ----
#define R_HT  0          // h[t] (16 slots); x tile spans 32 slots
#define R_OUT 8192       // gated out / y
#define R_CND 16384      // cond (12 slots; k=80 -> 1.0 bias col)
#define WB0   22528      // weight stage buf 0 (16384 shorts = 32 KB)
#define WB1   38912      // weight stage buf 1
#define LDS_SHORTS 55296 // 108 KB

// ---- weight pack (shorts): per layer 26 klines (kline = 8 frags x 512) ----
#define LS 106496
#define C1 16384
#define C2 32768
#define C3 49152
#define C4 57344
#define C5 73728
#define C6 90112
#define IN_OFF   3194880
#define OUT1_OFF 3227648
#define OUT2_OFF 3244032

__device__ __forceinline__ unsigned short f2bf_u(float f) {
    union { float f; unsigned u; } v; v.f = f;
    unsigned u = v.u + 0x7FFFu + ((v.u >> 16) & 1u);
    return (unsigned short)(u >> 16);
}
__device__ __forceinline__ short f2bf(float f) { return (short)f2bf_u(f); }

__device__ __forceinline__ unsigned cvtpk(float lo, float hi) {
    unsigned r;
    asm("v_cvt_pk_bf16_f32 %0, %1, %2" : "=v"(r) : "v"(lo), "v"(hi));
    return r;
}

__device__ __forceinline__ float gated_act(float av, float gv) {
    float e  = __expf(-2.f * fabsf(av));
    float th = (1.f - e) * __builtin_amdgcn_rcpf(1.f + e);
    th = (av < 0.f) ? -th : th;
    float sg = __builtin_amdgcn_rcpf(1.f + __expf(-gv));
    return th * sg;
}

__device__ __forceinline__ void ldg16_sc1(bf16x8* d, const short* p) {
    asm volatile("global_load_dwordx4 %0, %1, off sc1" : "=v"(*d) : "v"(p));
}
__device__ __forceinline__ void stg8_sc1(short* p, uint2v v) {
    asm volatile("global_store_dwordx2 %0, %1, off sc1" : : "v"(p), "v"(v) : "memory");
}
__device__ __forceinline__ void st_flag(int* p, int v) {
    __hip_atomic_store(p, v, __ATOMIC_RELAXED, __HIP_MEMORY_SCOPE_AGENT);
}
__device__ __forceinline__ void wait_ge(const int* p, int v) {
    while (__hip_atomic_load(p, __ATOMIC_RELAXED, __HIP_MEMORY_SCOPE_AGENT) < v)
        __builtin_amdgcn_s_sleep(1);
}

__device__ __forceinline__ f32x4 mfma_(bf16x8 a, bf16x8 b, f32x4 c) {
    return __builtin_amdgcn_mfma_f32_16x16x32_bf16(a, b, c, 0, 0, 0);
}

__device__ __forceinline__ void gload_lds16(const short* g, short* l) {
    __builtin_amdgcn_global_load_lds(
        (const __attribute__((address_space(1))) unsigned int*)g,
        (__attribute__((address_space(3))) unsigned int*)l, 16, 0, 0);
}
__device__ __forceinline__ void stageW2(const short* src, short* dst, int wv, int lane) {
    gload_lds16(src + wv * 512 + lane * 8, dst + wv * 512);
    gload_lds16(src + (16 + wv) * 512 + lane * 8, dst + (16 + wv) * 512);
}
__device__ __forceinline__ void stageW1(const short* src, short* dst, int wv, int lane) {
    gload_lds16(src + wv * 512 + lane * 8, dst + wv * 512);
}

// two A-streams (matrix pair), B from LDS slot table
template<int NP>
__device__ __forceinline__ void pairN(const short* wb, const short* sm, int boff,
                                      int ks0, int lg, int awoff,
                                      f32x4* ac0, f32x4* ac1)
{
#pragma unroll
    for (int p = 0; p < NP; ++p) {
        bf16x8 B = *(const bf16x8*)&sm[boff + ((ks0 + p) * 4 + lg) * 512];
#pragma unroll
        for (int mt = 0; mt < 2; ++mt) {
            bf16x8 a0 = *(const bf16x8*)&wb[p * 8192 + awoff + mt * 512];
            ac0[mt] = mfma_(a0, B, ac0[mt]);
            bf16x8 a1 = *(const bf16x8*)&wb[p * 8192 + 4096 + awoff + mt * 512];
            ac1[mt] = mfma_(a1, B, ac1[mt]);
        }
    }
}
template<int NP>
__device__ __forceinline__ void singleN(const short* wb, const short* sm, int boff,
                                        int ks0, int lg, int awoff, f32x4* ac)
{
#pragma unroll
    for (int p = 0; p < NP; ++p) {
        bf16x8 B = *(const bf16x8*)&sm[boff + ((ks0 + p) * 4 + lg) * 512];
#pragma unroll
        for (int mt = 0; mt < 2; ++mt) {
            bf16x8 a = *(const bf16x8*)&wb[p * 4096 + awoff + mt * 512];
            ac[mt] = mfma_(a, B, ac[mt]);
        }
    }
}

// ---------------- weight pack + flag/guard zero ----------------
__global__ __launch_bounds__(256) void k_pack(
    const float* __restrict__ dil_w, const float* __restrict__ gate_w,
    const float* __restrict__ cond_w, const float* __restrict__ condg_w,
    const float* __restrict__ res_w, const float* __restrict__ skip_w,
    const float* __restrict__ input_w, const float* __restrict__ out1_w,
    const float* __restrict__ out2_w,
    const float* __restrict__ dil_b, const float* __restrict__ cond_b,
    const float* __restrict__ gate_b, const float* __restrict__ condg_b,
    short* __restrict__ wp, short* __restrict__ hbt, int* __restrict__ flg)
{
    int gid = blockIdx.x * 256 + threadIdx.x;
    if (gid < 512) flg[gid] = 0;
    {
        int g2 = gid - 512;
        if (g2 >= 0 && g2 < 262144) {      // zero guard rows of 8 slabs
            unsigned* hb32 = (unsigned*)hbt;
            int slab = g2 >> 15, off = g2 & 32767;
            hb32[(size_t)slab * (SLAB / 2) + off] = 0u;
        }
    }
    if (gid >= 6400 * 64) return;
    int fid = gid >> 6, lane = gid & 63;
    int lr = lane & 15, lg = lane >> 4;
    float v[8];
    if (fid < 6240) {
        int layer = fid / 208;
        int r = fid - layer * 208;
        int kl = r >> 3, f = r & 7;
        int m = f * 16 + lr;
        size_t mi = (size_t)layer * 128 + m;
        int mat, ks;
        if      (kl < 8)  { mat = (kl & 1) ? 2 : 1; ks = kl >> 1; }        // g : d1
        else if (kl < 14) { mat = (kl & 1) ? 4 : 3; ks = (kl - 8) >> 1; }  // cg : c
        else if (kl < 18) { mat = 0; ks = kl - 14; }                       // d0
        else              { mat = (kl & 1) ? 6 : 5; ks = (kl - 18) >> 1; } // s : r
        int kb = ks * 32 + lg * 8;
#pragma unroll
        for (int e = 0; e < 8; ++e) {
            int k = kb + e;
            float val;
            switch (mat) {
                case 0:  val = dil_w[(mi * 128 + k) * 2];     break;
                case 1:  val = dil_w[(mi * 128 + k) * 2 + 1]; break;
                case 2:  val = gate_w[mi * 128 + k]; break;
                case 3:  val = (k < 80) ? cond_w[mi * 80 + k]
                               : ((k == 80) ? dil_b[mi] + cond_b[mi] : 0.f); break;
                case 4:  val = (k < 80) ? condg_w[mi * 80 + k]
                               : ((k == 80) ? gate_b[mi] + condg_b[mi] : 0.f); break;
                case 5:  val = res_w[mi * 128 + k]; break;
                default: val = skip_w[mi * 128 + k]; break;
            }
            v[e] = val;
        }
    } else if (fid < 6304) {               // input conv: 8 klines
        int f = fid - 6240; int ks = f >> 3, fr = f & 7;
        int m = fr * 16 + lr; int kb = ks * 32 + lg * 8;
#pragma unroll
        for (int e = 0; e < 8; ++e) v[e] = input_w[(size_t)m * 256 + kb + e];
    } else if (fid < 6336) {               // out1: 4 klines
        int f = fid - 6304; int ks = f >> 3, fr = f & 7;
        int m = fr * 16 + lr; int kb = ks * 32 + lg * 8;
#pragma unroll
        for (int e = 0; e < 8; ++e) v[e] = out1_w[(size_t)m * 128 + kb + e];
    } else {                               // out2: 8 klines (ks-major)
        int f = fid - 6336; int mt = f & 15; int ks = f >> 4;
        int m = mt * 16 + lr; int kb = ks * 32 + lg * 8;
#pragma unroll
        for (int e = 0; e < 8; ++e) v[e] = out2_w[(size_t)m * 128 + kb + e];
    }
    short* dst = wp + (size_t)fid * 512 + lane * 8;
#pragma unroll
    for (int e = 0; e < 8; ++e) dst[e] = f2bf(v[e]);
}

// ---------------- persistent fused WaveNet ----------------
__global__ __launch_bounds__(1024, 4) void k_wavenet(
    const float* __restrict__ x, const float* __restrict__ cond,
    const short* __restrict__ wp, short* __restrict__ hbt,
    const float* __restrict__ ib, const float* __restrict__ rbias,
    const float* __restrict__ sbias, const float* __restrict__ b1,
    const float* __restrict__ b2, float* __restrict__ outp,
    int* __restrict__ rdy, int* __restrict__ dn)
{
    __shared__ __align__(16) short sm[LDS_SHORTS];   // 108 KB

    const int tid  = threadIdx.x;
    const int lane = tid & 63;
    const int wv   = __builtin_amdgcn_readfirstlane(tid >> 6);   // 0..15
    const int wm   = wv & 3;
    const int wn   = wv >> 2;
    const int lr   = lane & 15, lg = lane >> 4;
    const int bidx = blockIdx.x;
    const int b    = bidx / NTPB;
    const int ti   = bidx - b * NTPB;
    const int t0   = ti * 64;
    const int tl   = wn * 16 + lr;
    const int tg   = t0 + tl;
    const int tl8  = tl * 8;
    const int lane8 = lane * 8;
    const int awoff = wm * 1024 + lane8;
    const int chA  = wm * 32 + lg * 4;
    const int kbA  = wm * 4 + (lg >> 1);
    const int e0   = (lg & 1) * 4;

    // ---- stage input-conv weights + x tile (slots 0..31) + cond tile ----
    stageW2(wp + IN_OFF, (short*)&sm[WB0], wv, lane);
    stageW2(wp + IN_OFF + 16384, (short*)&sm[WB1], wv, lane);
    {
        const float* xb = x + (size_t)b * 256 * T_LEN + t0 + lane;
#pragma unroll
        for (int it = 0; it < 2; ++it) {
            int kb = wv * 2 + it;              // 0..31
            unsigned pk[4];
#pragma unroll
            for (int e = 0; e < 4; ++e)
                pk[e] = cvtpk(xb[(size_t)(kb * 8 + 2 * e) * T_LEN],
                              xb[(size_t)(kb * 8 + 2 * e + 1) * T_LEN]);
            *(uint4v*)&sm[(kb * 64 + lane) * 8] = *(uint4v*)pk;
        }
        if (wv < 12) {
            const float* cb = cond + (size_t)b * 80 * T_LEN + t0 + lane;
            unsigned pk[4];
#pragma unroll
            for (int e = 0; e < 4; ++e) {
                int c0 = wv * 8 + 2 * e, c1 = c0 + 1;
                float v0 = (c0 < 80) ? cb[(size_t)c0 * T_LEN] : ((c0 == 80) ? 1.f : 0.f);
                float v1 = (c1 < 80) ? cb[(size_t)c1 * T_LEN] : 0.f;
                pk[e] = cvtpk(v0, v1);
            }
            *(uint4v*)&sm[R_CND + (wv * 64 + lane) * 8] = *(uint4v*)pk;
        }
    }
    __syncthreads();   // full drain: weights + x + cond ready

    // ---- input conv ----
    f32x4 hres[2] = {{0.f,0.f,0.f,0.f},{0.f,0.f,0.f,0.f}};
    {
        f32x4 acc[2] = {{0.f,0.f,0.f,0.f},{0.f,0.f,0.f,0.f}};
        singleN<4>((const short*)&sm[WB0], sm, tl8, 0, lg, awoff, acc);
        singleN<4>((const short*)&sm[WB1], sm, tl8, 4, lg, awoff, acc);
#pragma unroll
        for (int mt = 0; mt < 2; ++mt) {
            int cb0 = chA + mt * 16;
            f32x4 bv = {ib[cb0], ib[cb0 + 1], ib[cb0 + 2], ib[cb0 + 3]};
            hres[mt] = acc[mt] + bv;
        }
    }
    __syncthreads();   // all waves done reading x slots 0..15
    {
        short* hrow = hbt + (size_t)b * SLAB + (size_t)(GUARD + tg) * 128 + chA;
#pragma unroll
        for (int mt = 0; mt < 2; ++mt) {
            uint2v hv = {cvtpk(hres[mt][0], hres[mt][1]), cvtpk(hres[mt][2], hres[mt][3])};
            stg8_sc1(hrow + mt * 16, hv);
            *(uint2v*)&sm[R_HT + ((kbA + mt * 2) * 64 + tl) * 8 + e0] = hv;
        }
    }
    asm volatile("s_waitcnt vmcnt(0)" ::: "memory");
    __syncthreads();
    if (tid == 0) st_flag(&rdy[bidx], 1);

    f32x4 skp[2] = {{0.f,0.f,0.f,0.f},{0.f,0.f,0.f,0.f}};

    // ---- 30 layers (R6 skeleton; flag wait + Bg moved to phase D) ----
    for (int li = 0; li < NLAYER; ++li) {
        const int d   = 1 << (li % 10);
        const int ksh = (d + 63) >> 6;
        const short* wl  = wp + (size_t)li * LS;
        const short* hcb = hbt + (size_t)((li & 3) * 2 + b) * SLAB;
        short*       hnb = hbt + (size_t)(((li + 1) & 3) * 2 + b) * SLAB;

        stageW2(wl, (short*)&sm[WB0], wv, lane);                       // S0
        __syncthreads();                                               // barA: S0 ready
        stageW2(wl + C1, (short*)&sm[WB1], wv, lane);                  // S1
        f32x4 aa[2] = {{0.f,0.f,0.f,0.f},{0.f,0.f,0.f,0.f}};
        f32x4 ag[2] = {{0.f,0.f,0.f,0.f},{0.f,0.f,0.f,0.f}};
        pairN<2>((const short*)&sm[WB0], sm, R_HT + tl8, 0, lg, awoff, aa, ag);   // c0
        __syncthreads();                                               // barB: S1 ready
        stageW2(wl + C2, (short*)&sm[WB0], wv, lane);                  // S2
        pairN<2>((const short*)&sm[WB1], sm, R_HT + tl8, 2, lg, awoff, aa, ag);   // c1
        __syncthreads();                                               // barC: S2 ready
        stageW1(wl + C3, (short*)&sm[WB1], wv, lane);                  // S3 (16 KB)
        pairN<2>((const short*)&sm[WB0], sm, R_CND + tl8, 0, lg, awoff, aa, ag);  // c2
        __syncthreads();                                               // barD: S3 ready
        stageW2(wl + C4, (short*)&sm[WB0], wv, lane);                  // S4
        // ---- dependency wait + h[t-d] loads (moved here: ~4 phases of slack) ----
        if (lane == 0 && ti >= ksh) wait_ge(&rdy[bidx - ksh], li + 1);
        bf16x8 Bg[4];
        {
            const short* hr = hcb + (size_t)(GUARD + tg - d) * 128 + lg * 8;
#pragma unroll
            for (int ks = 0; ks < 4; ++ks) ldg16_sc1(&Bg[ks], hr + ks * 32);
        }
        pairN<1>((const short*)&sm[WB1], sm, R_CND + tl8, 2, lg, awoff, aa, ag);  // c3
        __syncthreads();                                               // barE: S4 + Bg landed
        if (tid == 0) st_flag(&dn[bidx], li + 1);                      // Bg loads retired
        stageW2(wl + C5, (short*)&sm[WB1], wv, lane);                  // S5
        {   // c4: d0 @ Bg (registers)
#pragma unroll
            for (int ks = 0; ks < 4; ++ks) {
#pragma unroll
                for (int mt = 0; mt < 2; ++mt) {
                    bf16x8 a = *(const bf16x8*)&sm[WB0 + ks * 4096 + awoff + mt * 512];
                    aa[mt] = mfma_(a, Bg[ks], aa[mt]);
                }
            }
        }
#pragma unroll
        for (int mt = 0; mt < 2; ++mt) {       // act -> R_OUT
            uint2v ov = {cvtpk(gated_act(aa[mt][0], ag[mt][0]), gated_act(aa[mt][1], ag[mt][1])),
                         cvtpk(gated_act(aa[mt][2], ag[mt][2]), gated_act(aa[mt][3], ag[mt][3]))};
            *(uint2v*)&sm[R_OUT + ((kbA + mt * 2) * 64 + tl) * 8 + e0] = ov;
        }
        __syncthreads();                                               // barF: S5 ready, R_OUT visible
        stageW2(wl + C6, (short*)&sm[WB0], wv, lane);                  // S6
        f32x4 ar[2]  = {{0.f,0.f,0.f,0.f},{0.f,0.f,0.f,0.f}};
        f32x4 as2[2] = {{0.f,0.f,0.f,0.f},{0.f,0.f,0.f,0.f}};
        pairN<2>((const short*)&sm[WB1], sm, R_OUT + tl8, 0, lg, awoff, ar, as2); // c5
        __syncthreads();                                               // barG: S6 ready
        pairN<2>((const short*)&sm[WB0], sm, R_OUT + tl8, 2, lg, awoff, ar, as2); // c6

        const float* rbl = rbias + li * 128 + chA;
        const float* sbl = sbias + li * 128 + chA;
#pragma unroll
        for (int mt = 0; mt < 2; ++mt) {
            f32x4 rbv = {rbl[mt*16], rbl[mt*16+1], rbl[mt*16+2], rbl[mt*16+3]};
            f32x4 sbv = {sbl[mt*16], sbl[mt*16+1], sbl[mt*16+2], sbl[mt*16+3]};
            skp[mt]  = skp[mt] + as2[mt] + sbv;
            hres[mt] = (hres[mt] + ar[mt] + rbv) * INV_SQRT2;
        }
        if (li < NLAYER - 1) {
            if (lane == 0 && li >= 3) {        // WAR vs readers of h^{li-3}
                int d3 = 1 << ((li - 3) % 10);
                int k3 = (d3 + 63) >> 6;
                if (ti + k3 < NTPB) wait_ge(&dn[bidx + k3], li - 2);
            }
            short* hrow = hnb + (size_t)(GUARD + tg) * 128 + chA;
#pragma unroll
            for (int mt = 0; mt < 2; ++mt) {
                uint2v hv = {cvtpk(hres[mt][0], hres[mt][1]), cvtpk(hres[mt][2], hres[mt][3])};
                stg8_sc1(hrow + mt * 16, hv);
                *(uint2v*)&sm[R_HT + ((kbA + mt * 2) * 64 + tl) * 8 + e0] = hv;
            }
        }
        asm volatile("s_waitcnt vmcnt(0)" ::: "memory");
        __syncthreads();                                               // barH: stores drained
        if (tid == 0 && li < NLAYER - 1) st_flag(&rdy[bidx], li + 2);
    }

    // ---- output head ----
#pragma unroll
    for (int mt = 0; mt < 2; ++mt) {           // skip -> R_HT
        uint2v sv = {cvtpk(skp[mt][0], skp[mt][1]), cvtpk(skp[mt][2], skp[mt][3])};
        *(uint2v*)&sm[R_HT + ((kbA + mt * 2) * 64 + tl) * 8 + e0] = sv;
    }
    stageW2(wp + OUT1_OFF, (short*)&sm[WB0], wv, lane);
    stageW2(wp + OUT2_OFF, (short*)&sm[WB1], wv, lane);
    __syncthreads();                           // skip visible; out1 + out2a ready
    f32x4 ay[2] = {{0.f,0.f,0.f,0.f},{0.f,0.f,0.f,0.f}};
    singleN<4>((const short*)&sm[WB0], sm, R_HT + tl8, 0, lg, awoff, ay);
#pragma unroll
    for (int mt = 0; mt < 2; ++mt) {           // y = relu(. + b1) -> R_OUT
        int cb0 = chA + mt * 16;
        float y0 = fmaxf(ay[mt][0] + b1[cb0],     0.f);
        float y1 = fmaxf(ay[mt][1] + b1[cb0 + 1], 0.f);
        float y2 = fmaxf(ay[mt][2] + b1[cb0 + 2], 0.f);
        float y3 = fmaxf(ay[mt][3] + b1[cb0 + 3], 0.f);
        uint2v yv = {cvtpk(y0, y1), cvtpk(y2, y3)};
        *(uint2v*)&sm[R_OUT + ((kbA + mt * 2) * 64 + tl) * 8 + e0] = yv;
    }
    __syncthreads();                           // y visible; WB0 free
    stageW2(wp + OUT2_OFF + 16384, (short*)&sm[WB0], wv, lane);
    f32x4 ao[4] = {{0.f,0.f,0.f,0.f},{0.f,0.f,0.f,0.f},
                   {0.f,0.f,0.f,0.f},{0.f,0.f,0.f,0.f}};
    {
        const short* wb = (const short*)&sm[WB1];
#pragma unroll
        for (int ksp = 0; ksp < 2; ++ksp) {
            bf16x8 B = *(const bf16x8*)&sm[R_OUT + tl8 + (ksp * 4 + lg) * 512];
#pragma unroll
            for (int mt = 0; mt < 4; ++mt) {
                int fg = 4 * wm + mt;
                bf16x8 A = *(const bf16x8*)&wb[(ksp * 2 + (fg >> 3)) * 4096 + (fg & 7) * 512 + lane8];
                ao[mt] = mfma_(A, B, ao[mt]);
            }
        }
    }
    __syncthreads();                           // out2b ready
    {
        const short* wb = (const short*)&sm[WB0];
#pragma unroll
        for (int ksp = 0; ksp < 2; ++ksp) {
            bf16x8 B = *(const bf16x8*)&sm[R_OUT + tl8 + ((2 + ksp) * 4 + lg) * 512];
#pragma unroll
            for (int mt = 0; mt < 4; ++mt) {
                int fg = 4 * wm + mt;
                bf16x8 A = *(const bf16x8*)&wb[(ksp * 2 + (fg >> 3)) * 4096 + (fg & 7) * 512 + lane8];
                ao[mt] = mfma_(A, B, ao[mt]);
            }
        }
    }
#pragma unroll
    for (int mt = 0; mt < 4; ++mt) {
        int ch2 = wm * 64 + mt * 16 + lg * 4;
        float* op = outp + ((size_t)(b * 256 + ch2)) * T_LEN + tg;
        op[0]         = ao[mt][0] + b2[ch2];
        op[T_LEN]     = ao[mt][1] + b2[ch2 + 1];
        op[2 * T_LEN] = ao[mt][2] + b2[ch2 + 2];
        op[3 * T_LEN] = ao[mt][3] + b2[ch2 + 3];
    }
}

extern "C" void kernel_launch(void* const* d_in, const int* in_sizes, int n_in,
                              void* d_out, int out_size, void* d_ws, size_t ws_size,
                              hipStream_t stream)
{
    const float* x       = (const float*)d_in[0];
    const float* cond    = (const float*)d_in[1];
    const float* input_w = (const float*)d_in[2];
    const float* input_b = (const float*)d_in[3];
    const float* dil_w   = (const float*)d_in[4];
    const float* dil_b   = (const float*)d_in[5];
    const float* gate_w  = (const float*)d_in[6];
    const float* gate_b  = (const float*)d_in[7];
    const float* cond_w  = (const float*)d_in[8];
    const float* cond_b  = (const float*)d_in[9];
    const float* condg_w = (const float*)d_in[10];
    const float* condg_b = (const float*)d_in[11];
    const float* res_w   = (const float*)d_in[12];
    const float* res_b   = (const float*)d_in[13];
    const float* skip_w  = (const float*)d_in[14];
    const float* skip_b  = (const float*)d_in[15];
    const float* out1_w  = (const float*)d_in[16];
    const float* out1_b  = (const float*)d_in[17];
    const float* out2_w  = (const float*)d_in[18];
    const float* out2_b  = (const float*)d_in[19];
    float* outp = (float*)d_out;

    short* wpk = (short*)d_ws;                         // 6400*512 shorts
    short* hbt = wpk + (size_t)6400 * 512;             // 8 slabs (4 levels x 2 batches)
    int*   flg = (int*)(hbt + (size_t)8 * SLAB);       // 512 ints
    int*   rdy = flg;
    int*   dn  = flg + 256;

    k_pack<<<1600, 256, 0, stream>>>(dil_w, gate_w, cond_w, condg_w, res_w, skip_w,
                                     input_w, out1_w, out2_w,
                                     dil_b, cond_b, gate_b, condg_b, wpk, hbt, flg);

    void* args[] = {(void*)&x, (void*)&cond, (void*)&wpk, (void*)&hbt,
                    (void*)&input_b, (void*)&res_b, (void*)&skip_b,
                    (void*)&out1_b, (void*)&out2_b, (void*)&outp,
                    (void*)&rdy, (void*)&dn};
    (void)hipLaunchCooperativeKernel((void*)k_wavenet, dim3(NBLK), dim3(1024), args, 0, stream);
}